// Round 8
// baseline (229.909 us; speedup 1.0000x reference)
//
#include <hip/hip_runtime.h>
#include <stdint.h>

// Problem dims
#define TOKENS 8192      // 4*2048
#define IN_F   3072
#define PAD_F  4096
#define N_OUT  4096
#define K_DIM  4096

using i32x4 = __attribute__((ext_vector_type(4))) int;

// -------- workspace layout (bytes) --------
#define Q_OFF    0
#define WQ_OFF   33554432
#define AINV_OFF 50331648
#define PART_OFF 50364416
#define WSC_OFF  50380800

__device__ __forceinline__ void gload_lds16(const void* g, void* l) {
    __builtin_amdgcn_global_load_lds(
        (__attribute__((address_space(1))) void*)(void*)g,
        (__attribute__((address_space(3))) void*)l,
        16, 0, 0);
}

// ---------------- weight absmean: partial sums ----------------
__global__ __launch_bounds__(256) void k_wabs(const float* __restrict__ w,
                                              float* __restrict__ partial) {
    int tid = threadIdx.x;
    const float4* w4 = (const float4*)(w + (size_t)blockIdx.x * 4096);
    float s = 0.f;
#pragma unroll
    for (int i = 0; i < 4; ++i) {
        float4 v = w4[tid + i * 256];
        s += fabsf(v.x) + fabsf(v.y) + fabsf(v.z) + fabsf(v.w);
    }
#pragma unroll
    for (int o = 32; o > 0; o >>= 1) s += __shfl_xor(s, o);
    __shared__ float rb[4];
    if ((tid & 63) == 0) rb[tid >> 6] = s;
    __syncthreads();
    if (tid == 0) partial[blockIdx.x] = rb[0] + rb[1] + rb[2] + rb[3];
}

// ---------------- finalize weight scale ----------------
__global__ __launch_bounds__(256) void k_wscale(const float* __restrict__ partial,
                                                float* __restrict__ wsp) {
    int tid = threadIdx.x;
    float s = 0.f;
#pragma unroll
    for (int i = 0; i < 16; ++i) s += partial[tid + i * 256];
#pragma unroll
    for (int o = 32; o > 0; o >>= 1) s += __shfl_xor(s, o);
    __shared__ float rb[4];
    if ((tid & 63) == 0) rb[tid >> 6] = s;
    __syncthreads();
    if (tid == 0)
        wsp[0] = fmaxf((rb[0] + rb[1] + rb[2] + rb[3]) * (1.0f / 16777216.0f), 1e-5f);
}

// ---------------- ternary weight quant ----------------
__global__ __launch_bounds__(256) void k_wquant(const float* __restrict__ w,
                                                const float* __restrict__ wsp,
                                                unsigned int* __restrict__ wq) {
    int idx = blockIdx.x * 256 + threadIdx.x;   // float4 group index
    float ws = wsp[0];
    float4 v = ((const float4*)w)[idx];
    int a = (int)rintf(v.x / ws); a = max(-1, min(1, a));
    int b = (int)rintf(v.y / ws); b = max(-1, min(1, b));
    int c = (int)rintf(v.z / ws); c = max(-1, min(1, c));
    int d = (int)rintf(v.w / ws); d = max(-1, min(1, d));
    unsigned int p = (unsigned)(a & 255) | ((unsigned)(b & 255) << 8) |
                     ((unsigned)(c & 255) << 16) | ((unsigned)(d & 255) << 24);
    wq[idx] = p;
}

// ---------------- fused LayerNorm + pad + FWHT + int8 absmax quant ----------------
__global__ __launch_bounds__(256) void k_lnfwht(const float* __restrict__ x,
                                                const float* __restrict__ gamma,
                                                const float* __restrict__ beta,
                                                signed char* __restrict__ q,
                                                float* __restrict__ ainv) {
    __shared__ float s[PAD_F];
    __shared__ float rb[8];
    int tid = threadIdx.x;
    int lane = tid & 63;
    int t = blockIdx.x;
    const float* xr = x + (size_t)t * IN_F;

    float v[16];
    float sum = 0.f;
#pragma unroll
    for (int i = 0; i < 12; ++i) { v[i] = xr[tid + i * 256]; sum += v[i]; }
    v[12] = v[13] = v[14] = v[15] = 0.f;
#pragma unroll
    for (int o = 32; o > 0; o >>= 1) sum += __shfl_xor(sum, o);
    if ((tid & 63) == 0) rb[tid >> 6] = sum;
    __syncthreads();
    float mu = (rb[0] + rb[1] + rb[2] + rb[3]) * (1.0f / 3072.0f);

    float s2 = 0.f;
#pragma unroll
    for (int i = 0; i < 12; ++i) { float d = v[i] - mu; s2 += d * d; }
#pragma unroll
    for (int o = 32; o > 0; o >>= 1) s2 += __shfl_xor(s2, o);
    if ((tid & 63) == 0) rb[4 + (tid >> 6)] = s2;
    __syncthreads();
    float var = (rb[4] + rb[5] + rb[6] + rb[7]) * (1.0f / 3072.0f);
    float rstd = 1.0f / sqrtf(var + 1e-6f);

#pragma unroll
    for (int i = 0; i < 12; ++i)
        v[i] = (v[i] - mu) * rstd * gamma[tid + i * 256] + beta[tid + i * 256];

    // FWHT group 1: bits 8-11 (register index i)
#pragma unroll
    for (int b = 1; b < 16; b <<= 1) {
#pragma unroll
        for (int i = 0; i < 16; ++i) {
            if (!(i & b)) {
                float a0 = v[i], b0 = v[i | b];
                v[i] = a0 + b0;
                v[i | b] = a0 - b0;
            }
        }
    }
    // group 2: bits 0-5 (lane) via shfl_xor
#pragma unroll
    for (int m = 1; m <= 32; m <<= 1) {
#pragma unroll
        for (int i = 0; i < 16; ++i) {
            float p = __shfl_xor(v[i], m);
            v[i] = (lane & m) ? (p - v[i]) : (v[i] + p);
        }
    }
    // group 3: bits 6-7 (wave id) via LDS
#pragma unroll
    for (int m = 64; m <= 128; m <<= 1) {
        __syncthreads();
#pragma unroll
        for (int i = 0; i < 16; ++i) s[tid + i * 256] = v[i];
        __syncthreads();
#pragma unroll
        for (int i = 0; i < 16; ++i) {
            float p = s[(tid ^ m) + i * 256];
            v[i] = (tid & m) ? (p - v[i]) : (v[i] + p);
        }
    }

    // absmax of fwht/64
    float mx = 0.f;
#pragma unroll
    for (int i = 0; i < 16; ++i) mx = fmaxf(mx, fabsf(v[i]));
#pragma unroll
    for (int o = 32; o > 0; o >>= 1) mx = fmaxf(mx, __shfl_xor(mx, o));
    __syncthreads();
    if ((tid & 63) == 0) rb[tid >> 6] = mx;
    __syncthreads();
    float amraw = fmaxf(fmaxf(rb[0], rb[1]), fmaxf(rb[2], rb[3]));
    float amax = fmaxf(amraw * (1.0f / 64.0f), 1e-5f);
    float scale = 127.0f / amax;
    if (tid == 0) ainv[t] = amax * (1.0f / 127.0f);

    signed char* qr = q + (size_t)t * PAD_F;
#pragma unroll
    for (int i = 0; i < 16; ++i) {
        int qi = (int)rintf(v[i] * (1.0f / 64.0f) * scale);
        qi = max(-128, min(127, qi));
        qr[tid + i * 256] = (signed char)qi;
    }
}

// ---------------- int8 MFMA GEMM, 256x256 tile, 4 waves of 128x128, BK=64 ----------------
// out[m][n] = (sum_k q[m][k]*t[n][k]) * wsc * ainv[m]
// 1 wave/SIMD (acc[8][8] = 256 AGPR + 128 frag VGPR): program order = issue order.
// Chunked {4 ds_read(next tile) -> 16 MFMA(cur)} x4, sched_barrier-pinned, so the
// LDS pipe (64 KB/tile reads) drains under the MFMA pipe (1307 cyc/tile).
// Paired-row LDS layout (round-6 verified, 0 bank conflicts): LDS row r (128B)
// holds matrix rows {2r,2r+1}, chunk (par,h) at position (par*4+h)^(r&7);
// staging pre-swizzles the GLOBAL source (rule #21).
// 4-buffer ring, counted vmcnt (8 gloads/wave/tile): VMW(16) steady, 8->0 peel.
#define BK 64
#define NT (K_DIM / BK)   // 64

#define VMW(n) asm volatile("s_waitcnt vmcnt(" #n ")" ::: "memory")
#define SB0()  __builtin_amdgcn_sched_barrier(0)

__global__ __launch_bounds__(256, 1) void k_gemm(const signed char* __restrict__ Aq,
                                                 const signed char* __restrict__ Wq,
                                                 const float* __restrict__ ainv,
                                                 const float* __restrict__ wsp,
                                                 float* __restrict__ out) {
    __shared__ signed char sA[4][128 * 128];   // 4 x 16 KB (128 LDS-rows x 128B)
    __shared__ signed char sB[4][128 * 128];

    int tid = threadIdx.x;
    int lane = tid & 63, wid = tid >> 6;      // 4 waves

    // XCD partition: XCD x owns bm in {4x..4x+3} (A L2-resident), sweeps bn.
    int bid = blockIdx.x;
    int xcd = bid & 7, li = bid >> 3;
    int bmb = xcd * 4 + (li & 3);
    int bnb = li >> 2;
    size_t bm0 = (size_t)bmb * 256, bn0 = (size_t)bnb * 256;

    int wm = wid >> 1, wn = wid & 1;          // 2M x 2N waves; wave tile 128x128

    // ---- staging decode: lane l writes LDS byte l*16 of a 1024B segment ----
    int rr = lane >> 3, pp = lane & 7;
    int Lg = pp ^ rr;
    int spar = Lg >> 2, sh = Lg & 3;
    const signed char* gA = Aq + (bm0 + (size_t)(wid * 64 + 2 * rr + spar)) * K_DIM + sh * 16;
    const signed char* gB = Wq + (bn0 + (size_t)(wid * 64 + 2 * rr + spar)) * K_DIM + sh * 16;

    // ---- fragment read constants (16x16x64: frag row fr, kseg hh) ----
    int fr = lane & 15, hh = lane >> 4;
    int pos = (((fr & 1) << 2) | hh) ^ (fr >> 1);
    int abase = (wm * 64 + (fr >> 1)) * 8 + pos;   // + mf*64
    int bbase = (wn * 64 + (fr >> 1)) * 8 + pos;   // + nf*64

    i32x4 acc[8][8];
#pragma unroll
    for (int m = 0; m < 8; ++m)
#pragma unroll
        for (int n = 0; n < 8; ++n) acc[m][n] = (i32x4){0, 0, 0, 0};

    i32x4 afA[8], bfA[8], afB[8], bfB[8];

    auto STAGE = [&](int b, int t) {
        size_t k0 = (size_t)t * BK;
#pragma unroll
        for (int i = 0; i < 4; ++i) {
            gload_lds16(gA + k0 + (size_t)i * 16 * K_DIM, &sA[b][(wid * 32 + i * 8) * 128]);
            gload_lds16(gB + k0 + (size_t)i * 16 * K_DIM, &sB[b][(wid * 32 + i * 8) * 128]);
        }
    };

#define LOAD4(VP, BASE, AF, LO) do {                                    \
    AF[LO]     = VP[BASE + (LO) * 64];                                  \
    AF[LO + 1] = VP[BASE + (LO + 1) * 64];                              \
    AF[LO + 2] = VP[BASE + (LO + 2) * 64];                              \
    AF[LO + 3] = VP[BASE + (LO + 3) * 64];                              \
} while (0)

#define MFMA16(AF, BF, M0) do {                                         \
    _Pragma("unroll")                                                   \
    for (int nf = 0; nf < 8; ++nf) {                                    \
        acc[M0][nf] = __builtin_amdgcn_mfma_i32_16x16x64_i8(            \
            AF[M0], BF[nf], acc[M0][nf], 0, 0, 0);                      \
        acc[M0 + 1][nf] = __builtin_amdgcn_mfma_i32_16x16x64_i8(        \
            AF[M0 + 1], BF[nf], acc[M0 + 1][nf], 0, 0, 0);              \
    }                                                                   \
} while (0)

// One K-tile: stage T+3; certify T+1; 4 chunks of {4 ds_read(T+1) -> 16 MFMA(T)}
#define BODYC(T, NW, DS, AFC, BFC, AFN, BFN) do {                       \
    if (DS) STAGE((T + 3) & 3, T + 3);                                  \
    VMW(NW);                                                            \
    SB0();                                                              \
    __builtin_amdgcn_s_barrier();                                       \
    SB0();                                                              \
    const i32x4* va = (const i32x4*)&sA[(T + 1) & 3][0];                \
    const i32x4* vb = (const i32x4*)&sB[(T + 1) & 3][0];                \
    LOAD4(va, abase, AFN, 0); SB0(); MFMA16(AFC, BFC, 0); SB0();        \
    LOAD4(va, abase, AFN, 4); SB0(); MFMA16(AFC, BFC, 2); SB0();        \
    LOAD4(vb, bbase, BFN, 0); SB0(); MFMA16(AFC, BFC, 4); SB0();        \
    LOAD4(vb, bbase, BFN, 4); SB0(); MFMA16(AFC, BFC, 6); SB0();        \
    asm volatile("s_waitcnt lgkmcnt(0)" ::: "memory");                  \
    SB0();                                                              \
} while (0)

    // prologue: 3 tiles in flight (24 loads), tile 0 certified, frags(0) -> A set
    STAGE(0, 0);
    STAGE(1, 1);
    STAGE(2, 2);
    VMW(16);
    SB0();
    __builtin_amdgcn_s_barrier();
    SB0();
    {
        const i32x4* va = (const i32x4*)&sA[0][0];
        const i32x4* vb = (const i32x4*)&sB[0][0];
        LOAD4(va, abase, afA, 0);
        LOAD4(va, abase, afA, 4);
        LOAD4(vb, bbase, bfA, 0);
        LOAD4(vb, bbase, bfA, 4);
    }
    asm volatile("s_waitcnt lgkmcnt(0)" ::: "memory");
    SB0();

#pragma unroll 1
    for (int t = 0; t < NT - 4; t += 2) {
        BODYC(t, 16, true, afA, bfA, afB, bfB);
        BODYC(t + 1, 16, true, afB, bfB, afA, bfA);
    }
    // t = 60 (even): stages 63, certifies 61, computes 60(A), loads 61->B
    BODYC(NT - 4, 16, true, afA, bfA, afB, bfB);
    // t = 61: in flight 62,63 (16) -> VMW(8) certifies 62; computes 61(B), loads 62->A
    BODYC(NT - 3, 8, false, afB, bfB, afA, bfA);
    // t = 62: VMW(0) certifies 63; computes 62(A), loads 63->B
    BODYC(NT - 2, 0, false, afA, bfA, afB, bfB);
    // t = 63: compute only
    MFMA16(afB, bfB, 0);
    MFMA16(afB, bfB, 2);
    MFMA16(afB, bfB, 4);
    MFMA16(afB, bfB, 6);

    // epilogue: 16x16 C/D layout: col = lane&15, row = (lane>>4)*4 + reg
    float wsc = wsp[0];
#pragma unroll
    for (int mf = 0; mf < 8; ++mf) {
        size_t row0 = bm0 + wm * 128 + mf * 16 + hh * 4;
#pragma unroll
        for (int r = 0; r < 4; ++r) {
            size_t row = row0 + r;
            float sa = wsc * ainv[row];
#pragma unroll
            for (int nf = 0; nf < 8; ++nf) {
                size_t col = bn0 + wn * 128 + nf * 16 + fr;
                out[row * N_OUT + col] = (float)acc[mf][nf][r] * sa;
            }
        }
    }
#undef LOAD4
#undef MFMA16
#undef BODYC
}

extern "C" void kernel_launch(void* const* d_in, const int* in_sizes, int n_in,
                              void* d_out, int out_size, void* d_ws, size_t ws_size,
                              hipStream_t stream) {
    const float* x     = (const float*)d_in[0];
    const float* gamma = (const float*)d_in[1];
    const float* beta  = (const float*)d_in[2];
    const float* w     = (const float*)d_in[3];
    float* out = (float*)d_out;
    char* ws = (char*)d_ws;

    signed char* q   = (signed char*)(ws + Q_OFF);
    signed char* wq  = (signed char*)(ws + WQ_OFF);
    float* ainv      = (float*)(ws + AINV_OFF);
    float* partial   = (float*)(ws + PART_OFF);
    float* wsp       = (float*)(ws + WSC_OFF);

    k_wabs<<<dim3(4096), dim3(256), 0, stream>>>(w, partial);
    k_wscale<<<dim3(1), dim3(256), 0, stream>>>(partial, wsp);
    k_wquant<<<dim3(16384), dim3(256), 0, stream>>>(w, wsp, (unsigned int*)wq);
    k_lnfwht<<<dim3(TOKENS), dim3(256), 0, stream>>>(x, gamma, beta, q, ainv);
    k_gemm<<<dim3(512), dim3(256), 0, stream>>>(q, wq, ainv, wsp, out);
}

// Round 9
// 224.128 us; speedup vs baseline: 1.0258x; 1.0258x over previous
//
#include <hip/hip_runtime.h>
#include <stdint.h>

// Problem dims
#define TOKENS 8192      // 4*2048
#define IN_F   3072
#define PAD_F  4096
#define N_OUT  4096
#define K_DIM  4096

using i32x4 = __attribute__((ext_vector_type(4))) int;

// -------- workspace layout (bytes) --------
#define Q_OFF    0
#define WQ_OFF   33554432
#define AINV_OFF 50331648
#define PART_OFF 50364416
#define WSC_OFF  50380800

__device__ __forceinline__ void gload_lds16(const void* g, void* l) {
    __builtin_amdgcn_global_load_lds(
        (__attribute__((address_space(1))) void*)(void*)g,
        (__attribute__((address_space(3))) void*)l,
        16, 0, 0);
}

// ---------------- weight absmean: partial sums ----------------
__global__ __launch_bounds__(256) void k_wabs(const float* __restrict__ w,
                                              float* __restrict__ partial) {
    int tid = threadIdx.x;
    const float4* w4 = (const float4*)(w + (size_t)blockIdx.x * 4096);
    float s = 0.f;
#pragma unroll
    for (int i = 0; i < 4; ++i) {
        float4 v = w4[tid + i * 256];
        s += fabsf(v.x) + fabsf(v.y) + fabsf(v.z) + fabsf(v.w);
    }
#pragma unroll
    for (int o = 32; o > 0; o >>= 1) s += __shfl_xor(s, o);
    __shared__ float rb[4];
    if ((tid & 63) == 0) rb[tid >> 6] = s;
    __syncthreads();
    if (tid == 0) partial[blockIdx.x] = rb[0] + rb[1] + rb[2] + rb[3];
}

// ---------------- finalize weight scale ----------------
__global__ __launch_bounds__(256) void k_wscale(const float* __restrict__ partial,
                                                float* __restrict__ wsp) {
    int tid = threadIdx.x;
    float s = 0.f;
#pragma unroll
    for (int i = 0; i < 16; ++i) s += partial[tid + i * 256];
#pragma unroll
    for (int o = 32; o > 0; o >>= 1) s += __shfl_xor(s, o);
    __shared__ float rb[4];
    if ((tid & 63) == 0) rb[tid >> 6] = s;
    __syncthreads();
    if (tid == 0)
        wsp[0] = fmaxf((rb[0] + rb[1] + rb[2] + rb[3]) * (1.0f / 16777216.0f), 1e-5f);
}

// ---------------- ternary weight quant ----------------
__global__ __launch_bounds__(256) void k_wquant(const float* __restrict__ w,
                                                const float* __restrict__ wsp,
                                                unsigned int* __restrict__ wq) {
    int idx = blockIdx.x * 256 + threadIdx.x;   // float4 group index
    float ws = wsp[0];
    float4 v = ((const float4*)w)[idx];
    int a = (int)rintf(v.x / ws); a = max(-1, min(1, a));
    int b = (int)rintf(v.y / ws); b = max(-1, min(1, b));
    int c = (int)rintf(v.z / ws); c = max(-1, min(1, c));
    int d = (int)rintf(v.w / ws); d = max(-1, min(1, d));
    unsigned int p = (unsigned)(a & 255) | ((unsigned)(b & 255) << 8) |
                     ((unsigned)(c & 255) << 16) | ((unsigned)(d & 255) << 24);
    wq[idx] = p;
}

// ---------------- fused LayerNorm + pad + FWHT + int8 absmax quant ----------------
__global__ __launch_bounds__(256) void k_lnfwht(const float* __restrict__ x,
                                                const float* __restrict__ gamma,
                                                const float* __restrict__ beta,
                                                signed char* __restrict__ q,
                                                float* __restrict__ ainv) {
    __shared__ float s[PAD_F];
    __shared__ float rb[8];
    int tid = threadIdx.x;
    int lane = tid & 63;
    int t = blockIdx.x;
    const float* xr = x + (size_t)t * IN_F;

    float v[16];
    float sum = 0.f;
#pragma unroll
    for (int i = 0; i < 12; ++i) { v[i] = xr[tid + i * 256]; sum += v[i]; }
    v[12] = v[13] = v[14] = v[15] = 0.f;
#pragma unroll
    for (int o = 32; o > 0; o >>= 1) sum += __shfl_xor(sum, o);
    if ((tid & 63) == 0) rb[tid >> 6] = sum;
    __syncthreads();
    float mu = (rb[0] + rb[1] + rb[2] + rb[3]) * (1.0f / 3072.0f);

    float s2 = 0.f;
#pragma unroll
    for (int i = 0; i < 12; ++i) { float d = v[i] - mu; s2 += d * d; }
#pragma unroll
    for (int o = 32; o > 0; o >>= 1) s2 += __shfl_xor(s2, o);
    if ((tid & 63) == 0) rb[4 + (tid >> 6)] = s2;
    __syncthreads();
    float var = (rb[4] + rb[5] + rb[6] + rb[7]) * (1.0f / 3072.0f);
    float rstd = 1.0f / sqrtf(var + 1e-6f);

#pragma unroll
    for (int i = 0; i < 12; ++i)
        v[i] = (v[i] - mu) * rstd * gamma[tid + i * 256] + beta[tid + i * 256];

    // FWHT group 1: bits 8-11 (register index i)
#pragma unroll
    for (int b = 1; b < 16; b <<= 1) {
#pragma unroll
        for (int i = 0; i < 16; ++i) {
            if (!(i & b)) {
                float a0 = v[i], b0 = v[i | b];
                v[i] = a0 + b0;
                v[i | b] = a0 - b0;
            }
        }
    }
    // group 2: bits 0-5 (lane) via shfl_xor
#pragma unroll
    for (int m = 1; m <= 32; m <<= 1) {
#pragma unroll
        for (int i = 0; i < 16; ++i) {
            float p = __shfl_xor(v[i], m);
            v[i] = (lane & m) ? (p - v[i]) : (v[i] + p);
        }
    }
    // group 3: bits 6-7 (wave id) via LDS
#pragma unroll
    for (int m = 64; m <= 128; m <<= 1) {
        __syncthreads();
#pragma unroll
        for (int i = 0; i < 16; ++i) s[tid + i * 256] = v[i];
        __syncthreads();
#pragma unroll
        for (int i = 0; i < 16; ++i) {
            float p = s[(tid ^ m) + i * 256];
            v[i] = (tid & m) ? (p - v[i]) : (v[i] + p);
        }
    }

    // absmax of fwht/64
    float mx = 0.f;
#pragma unroll
    for (int i = 0; i < 16; ++i) mx = fmaxf(mx, fabsf(v[i]));
#pragma unroll
    for (int o = 32; o > 0; o >>= 1) mx = fmaxf(mx, __shfl_xor(mx, o));
    __syncthreads();
    if ((tid & 63) == 0) rb[tid >> 6] = mx;
    __syncthreads();
    float amraw = fmaxf(fmaxf(rb[0], rb[1]), fmaxf(rb[2], rb[3]));
    float amax = fmaxf(amraw * (1.0f / 64.0f), 1e-5f);
    float scale = 127.0f / amax;
    if (tid == 0) ainv[t] = amax * (1.0f / 127.0f);

    signed char* qr = q + (size_t)t * PAD_F;
#pragma unroll
    for (int i = 0; i < 16; ++i) {
        int qi = (int)rintf(v[i] * (1.0f / 64.0f) * scale);
        qi = max(-128, min(127, qi));
        qr[tid + i * 256] = (signed char)qi;
    }
}

// ---------------- int8 MFMA GEMM, 256x128 tile, 8 waves of 64x64, BK=64 ----------------
// out[m][n] = (sum_k q[m][k]*t[n][k]) * wsc * ainv[m]
// TWO blocks per CU (72 KB LDS, <=128 regs via __launch_bounds__(512,4)):
// independent blocks have no shared barrier -> one block's ds_read phase
// overlaps the other's MFMA phase (cross-block pipe overlap, m114 mechanism).
// Paired-row LDS layout (round-6 verified, 0 bank conflicts): LDS row r (128B)
// holds matrix rows {2r,2r+1}, chunk (par,h) at position (par*4+h)^(r&7);
// staging pre-swizzles the GLOBAL source (rule #21).
// 3-buffer ring, 1 barrier/tile, counted vmcnt: per tile
//   [s_barrier; STAGE(t+2); vmcnt(3); ds_read frags(t); MFMA(t)]
// Race-free: buffer (t+2)%3 was last read at tile t-1, and this tile's barrier
// separates those reads from the overwrite. Cross-wave certification of
// buf[t]: every wave's vmcnt(3) at tile t-1 forced its t-loads to land, and
// this tile's barrier publishes that.
#define BK 64
#define NT (K_DIM / BK)   // 64

#define VMW(n) asm volatile("s_waitcnt vmcnt(" #n ")" ::: "memory")
#define SB0()  __builtin_amdgcn_sched_barrier(0)

__global__ __launch_bounds__(512, 4) void k_gemm(const signed char* __restrict__ Aq,
                                                 const signed char* __restrict__ Wq,
                                                 const float* __restrict__ ainv,
                                                 const float* __restrict__ wsp,
                                                 float* __restrict__ out) {
    __shared__ signed char sA[3][128 * 128];   // 3 x 16 KB (A: 256 rows -> 128 LDS-rows)
    __shared__ signed char sB[3][64 * 128];    // 3 x  8 KB (B: 128 rows ->  64 LDS-rows)

    int tid = threadIdx.x;
    int lane = tid & 63, wid = tid >> 6;      // 8 waves

    // XCD partition: 1024 blocks (%8==0). XCD x owns bmb in {4x..4x+3}
    // (A panel 4 MB, L2-resident); bmb-inner so B panel (512 KB) reused 4x.
    int bid = blockIdx.x;
    int xcd = bid & 7, li = bid >> 3;          // li in [0,128)
    int bmb = xcd * 4 + (li & 3);              // 32 row-blocks of 256
    int bnb = li >> 2;                         // 32 col-blocks of 128
    size_t bm0 = (size_t)bmb * 256, bn0 = (size_t)bnb * 128;

    int wm = wid >> 1, wn = wid & 1;           // 4M x 2N waves; wave tile 64x64

    // ---- staging decode: lane l writes LDS byte l*16 of a 1024B segment ----
    // seg = 8 LDS-rows = 16 matrix rows. rr = LDS-row-in-seg, slot pp;
    // logical chunk L = pp ^ rr; par = L>>2 (row parity), h = L&3 (16B K-chunk).
    int rr = lane >> 3, pp = lane & 7;
    int Lg = pp ^ rr;
    int spar = Lg >> 2, sh = Lg & 3;
    // A: wave stages 2 segments (32 rows); B: 1 segment (16 rows)
    const signed char* gA = Aq + (bm0 + (size_t)(wid * 32 + 2 * rr + spar)) * K_DIM + sh * 16;
    const signed char* gB = Wq + (bn0 + (size_t)(wid * 16 + 2 * rr + spar)) * K_DIM + sh * 16;

    // ---- fragment read constants (16x16x64: frag row fr, kseg hh) ----
    int fr = lane & 15, hh = lane >> 4;
    int pos = (((fr & 1) << 2) | hh) ^ (fr >> 1);
    int abase = (wm * 32 + (fr >> 1)) * 8 + pos;   // + mf*64   (mf in [0,4))
    int bbase = (wn * 32 + (fr >> 1)) * 8 + pos;   // + nf*64   (nf in [0,4))

    i32x4 acc[4][4];
#pragma unroll
    for (int m = 0; m < 4; ++m)
#pragma unroll
        for (int n = 0; n < 4; ++n) acc[m][n] = (i32x4){0, 0, 0, 0};

    auto STAGE = [&](int b, int t) {
        size_t k0 = (size_t)t * BK;
        gload_lds16(gA + k0, &sA[b][(wid * 16) * 128]);
        gload_lds16(gA + k0 + (size_t)16 * K_DIM, &sA[b][(wid * 16 + 8) * 128]);
        gload_lds16(gB + k0, &sB[b][(wid * 8) * 128]);
    };

#define TILE_COMPUTE(B) do {                                            \
    const i32x4* va = (const i32x4*)&sA[B][0];                          \
    const i32x4* vb = (const i32x4*)&sB[B][0];                          \
    i32x4 af[4], bf[4];                                                 \
    _Pragma("unroll")                                                   \
    for (int mf = 0; mf < 4; ++mf) af[mf] = va[abase + mf * 64];        \
    _Pragma("unroll")                                                   \
    for (int nf = 0; nf < 4; ++nf) bf[nf] = vb[bbase + nf * 64];        \
    __builtin_amdgcn_s_setprio(1);                                      \
    _Pragma("unroll")                                                   \
    for (int mf = 0; mf < 4; ++mf)                                      \
        _Pragma("unroll")                                               \
        for (int nf = 0; nf < 4; ++nf)                                  \
            acc[mf][nf] = __builtin_amdgcn_mfma_i32_16x16x64_i8(        \
                af[mf], bf[nf], acc[mf][nf], 0, 0, 0);                  \
    __builtin_amdgcn_s_setprio(0);                                      \
} while (0)

    // prologue: stage tiles 0,1 (6 loads in flight); own t0 loads landed
    STAGE(0, 0);
    STAGE(1, 1);
    VMW(3);
    SB0();

#pragma unroll 1
    for (int t = 0; t < NT - 2; ++t) {
        __builtin_amdgcn_s_barrier();      // publishes buf[t] (all waves' vmcnt)
        SB0();                             // and frees buf[(t+2)%3] for overwrite
        STAGE((t + 2) % 3, t + 2);
        VMW(3);                            // own t+1 loads landed (for next tile)
        SB0();
        TILE_COMPUTE(t % 3);
    }
    // t = NT-2: last tile's loads (NT-1) must all land
    __builtin_amdgcn_s_barrier();
    SB0();
    VMW(0);
    SB0();
    TILE_COMPUTE((NT - 2) % 3);
    // t = NT-1
    __builtin_amdgcn_s_barrier();
    SB0();
    TILE_COMPUTE((NT - 1) % 3);

    // epilogue: 16x16 C/D layout: col = lane&15, row = (lane>>4)*4 + reg
    float wsc = wsp[0];
#pragma unroll
    for (int mf = 0; mf < 4; ++mf) {
        size_t row0 = bm0 + wm * 64 + mf * 16 + hh * 4;
#pragma unroll
        for (int r = 0; r < 4; ++r) {
            size_t row = row0 + r;
            float sa = wsc * ainv[row];
#pragma unroll
            for (int nf = 0; nf < 4; ++nf) {
                size_t col = bn0 + wn * 64 + nf * 16 + fr;
                out[row * N_OUT + col] = (float)acc[mf][nf][r] * sa;
            }
        }
    }
#undef TILE_COMPUTE
}

extern "C" void kernel_launch(void* const* d_in, const int* in_sizes, int n_in,
                              void* d_out, int out_size, void* d_ws, size_t ws_size,
                              hipStream_t stream) {
    const float* x     = (const float*)d_in[0];
    const float* gamma = (const float*)d_in[1];
    const float* beta  = (const float*)d_in[2];
    const float* w     = (const float*)d_in[3];
    float* out = (float*)d_out;
    char* ws = (char*)d_ws;

    signed char* q   = (signed char*)(ws + Q_OFF);
    signed char* wq  = (signed char*)(ws + WQ_OFF);
    float* ainv      = (float*)(ws + AINV_OFF);
    float* partial   = (float*)(ws + PART_OFF);
    float* wsp       = (float*)(ws + WSC_OFF);

    k_wabs<<<dim3(4096), dim3(256), 0, stream>>>(w, partial);
    k_wscale<<<dim3(1), dim3(256), 0, stream>>>(partial, wsp);
    k_wquant<<<dim3(16384), dim3(256), 0, stream>>>(w, wsp, (unsigned int*)wq);
    k_lnfwht<<<dim3(TOKENS), dim3(256), 0, stream>>>(x, gamma, beta, q, ainv);
    k_gemm<<<dim3(1024), dim3(512), 0, stream>>>(q, wq, ainv, wsp, out);
}